// Round 8
// baseline (694.694 us; speedup 1.0000x reference)
//
#include <hip/hip_runtime.h>

#define RH 32
#define RT 2048
#define RC 10

typedef __attribute__((ext_vector_type(8))) _Float16 f16x8;
typedef __attribute__((ext_vector_type(4))) float f32x4;

#define MFMA16(a,b,c) __builtin_amdgcn_mfma_f32_16x16x32_f16((a),(b),(c),0,0,0)

// tanh(x) = 1 - 2/(exp(2x)+1); saturates correctly at +/-inf.
__device__ __forceinline__ float fast_tanh(float x) {
    float e = __builtin_amdgcn_exp2f(x * 2.88539008177792681472f);
    return fmaf(-2.0f, __builtin_amdgcn_rcpf(e + 1.0f), 1.0f);
}

// A-frag rows [base,base+16): lane(n,g) holds W[base+n][k], k = 4g+(e&3)+16*(e>>2)
// (layout validated end-to-end in rounds 4, 5, 7)
__device__ __forceinline__ f16x8 load_wfrag16(const float* __restrict__ W,
                                              int base, int n, int g) {
    f16x8 f;
#pragma unroll
    for (int e = 0; e < 8; ++e) {
        int k = 4*g + (e & 3) + 16*(e >> 2);
        f[e] = (_Float16)W[(base + n)*RH + k];   // RNE
    }
    return f;
}

__global__ __launch_bounds__(64) void rnn2_ldsx_kernel(
    const float* __restrict__ x,
    const float* __restrict__ W_ih0, const float* __restrict__ W_hh0,
    const float* __restrict__ b_ih0, const float* __restrict__ b_hh0,
    const float* __restrict__ W_ih1, const float* __restrict__ W_hh1,
    const float* __restrict__ b_ih1, const float* __restrict__ b_hh1,
    const float* __restrict__ fc_w, const float* __restrict__ fc_b,
    float* __restrict__ out)
{
    // x ring: [slot][step][batch][h] = 4 x 8 x 16 x 32 f32 = 64 KiB.
    // Column-swizzled: LDS[n][c16] holds x 16B-col (c16 ^ (n&7)).
    __shared__ __align__(16) float xs[4][8][16][32];
    __shared__ float h2fin[16][RH];

    const int ln = threadIdx.x;      // single wave per block
    const int n  = ln & 15;          // batch column within 16-batch tile
    const int g  = ln >> 4;          // row/k 4-group

    // All 8 weight tile-fragments in registers (f16).
    f16x8 WI0a = load_wfrag16(W_ih0,  0, n, g);
    f16x8 WI0b = load_wfrag16(W_ih0, 16, n, g);
    f16x8 WH0a = load_wfrag16(W_hh0,  0, n, g);
    f16x8 WH0b = load_wfrag16(W_hh0, 16, n, g);
    f16x8 WI1a = load_wfrag16(W_ih1,  0, n, g);
    f16x8 WI1b = load_wfrag16(W_ih1, 16, n, g);
    f16x8 WH1a = load_wfrag16(W_hh1,  0, n, g);
    f16x8 WH1b = load_wfrag16(W_hh1, 16, n, g);

    f32x4 cb1a, cb1b, cb2a, cb2b;    // bias C-frags (rows 4g+i / 16+4g+i)
#pragma unroll
    for (int i = 0; i < 4; ++i) {
        cb1a[i] = b_ih0[4*g + i]      + b_hh0[4*g + i];
        cb1b[i] = b_ih0[16 + 4*g + i] + b_hh0[16 + 4*g + i];
        cb2a[i] = b_ih1[4*g + i]      + b_hh1[4*g + i];
        cb2b[i] = b_ih1[16 + 4*g + i] + b_hh1[16 + 4*g + i];
    }

    f16x8 h1f, h2f;                  // recurrent states (D-frag == next B-frag)
#pragma unroll
    for (int e = 0; e < 8; ++e) { h1f[e] = (_Float16)0.0f; h2f[e] = (_Float16)0.0f; }

    // ---- staging (write side) ----
    // 16 global_load_lds per 8-step chunk; instr s: step s>>1, batch-half s&1.
    // Lane ln -> LDS slot byte ln*16 = [batch hb*8 + (ln>>3)][16B-col ln&7].
    // Source pre-swizzled so LDS[n][c] = x 16B-col (c ^ (n&7)).
    const int nn8 = ln >> 3;                 // batch-within-half
    const int cs  = (ln & 7) ^ nn8;          // swizzled source 16B-col
    const float* xstage = x + (size_t)(blockIdx.x*16 + nn8) * (RT*RH) + cs*4;

#define STAGE(SLOT_) do {                                                     \
    _Pragma("unroll")                                                         \
    for (int s_ = 0; s_ < 16; ++s_) {                                         \
        const int st_ = s_ >> 1, hb_ = s_ & 1;                                \
        __builtin_amdgcn_global_load_lds(                                     \
            (const __attribute__((address_space(1))) void*)                  \
                (xstage + (size_t)hb_*8*RT*RH + st_*RH),                      \
            (__attribute__((address_space(3))) void*)&xs[SLOT_][st_][hb_*8][0],\
            16, 0, 0);                                                        \
    }                                                                         \
    xstage += 8*RH;                                                           \
} while (0)

#define WAITV(N_) __asm__ volatile("s_waitcnt vmcnt(" #N_ ")" ::: "memory")

    // ---- read side ----
    const int c1 = g ^ (n & 7);
    const int c2 = (g + 4) ^ (n & 7);
    const char* xb1 = (const char*)xs + n*128 + c1*16;
    const char* xb2 = (const char*)xs + n*128 + c2*16;

#define CVTX(dst_, A_, B_) do { \
    auto q0_ = __builtin_amdgcn_cvt_pkrtz(A_.x, A_.y); \
    auto q1_ = __builtin_amdgcn_cvt_pkrtz(A_.z, A_.w); \
    auto q2_ = __builtin_amdgcn_cvt_pkrtz(B_.x, B_.y); \
    auto q3_ = __builtin_amdgcn_cvt_pkrtz(B_.z, B_.w); \
    dst_[0] = q0_[0]; dst_[1] = q0_[1]; dst_[2] = q1_[0]; dst_[3] = q1_[1]; \
    dst_[4] = q2_[0]; dst_[5] = q2_[1]; dst_[6] = q3_[0]; dst_[7] = q3_[1]; \
} while (0)

#define LOADX(xf_, SLOT_, ST_) do { \
    float4 a_ = *(const float4*)(xb1 + (SLOT_)*16384 + (ST_)*2048); \
    float4 b_ = *(const float4*)(xb2 + (SLOT_)*16384 + (ST_)*2048); \
    CVTX(xf_, a_, b_); \
} while (0)

    // Staggered step: L1 makes h1(t) from h1f; L2 makes h2(t-1) from the SAME
    // pre-update h1f and h2f. Arithmetic identical to round 7 (bit-exact).
#define STEP(SLOT_, ST_) do { \
    f16x8 xf_; LOADX(xf_, SLOT_, ST_); \
    f32x4 e0_ = MFMA16(WI1a, h1f, cb2a); \
    f32x4 e1_ = MFMA16(WI1b, h1f, cb2b); \
    f32x4 d0_ = MFMA16(WI0a, xf_, cb1a); \
    f32x4 d1_ = MFMA16(WI0b, xf_, cb1b); \
    e0_ = MFMA16(WH1a, h2f, e0_); \
    e1_ = MFMA16(WH1b, h2f, e1_); \
    d0_ = MFMA16(WH0a, h1f, d0_); \
    d1_ = MFMA16(WH0b, h1f, d1_); \
    _Pragma("unroll") \
    for (int i_ = 0; i_ < 4; ++i_) { e0_[i_] = fast_tanh(e0_[i_]); e1_[i_] = fast_tanh(e1_[i_]); } \
    _Pragma("unroll") \
    for (int i_ = 0; i_ < 4; ++i_) { h2f[i_] = (_Float16)e0_[i_]; h2f[4+i_] = (_Float16)e1_[i_]; } \
    _Pragma("unroll") \
    for (int i_ = 0; i_ < 4; ++i_) { d0_[i_] = fast_tanh(d0_[i_]); d1_[i_] = fast_tanh(d1_[i_]); } \
    _Pragma("unroll") \
    for (int i_ = 0; i_ < 4; ++i_) { h1f[i_] = (_Float16)d0_[i_]; h1f[4+i_] = (_Float16)d1_[i_]; } \
} while (0)

#define CHUNK8(SLOT_) do { \
    STEP(SLOT_, 0); STEP(SLOT_, 1); STEP(SLOT_, 2); STEP(SLOT_, 3); \
    STEP(SLOT_, 4); STEP(SLOT_, 5); STEP(SLOT_, 6); STEP(SLOT_, 7); \
} while (0)

    // ---- main ----
    STAGE(0); STAGE(1); STAGE(2); STAGE(3);   // chunks 0..3 in flight (64 loads)
    WAITV(48);                                 // chunk 0 landed

    {   // chunk 0: t=0 prologue (L1 only; WH0*0 == 0 exactly), then t=1..7
        f16x8 xf0; LOADX(xf0, 0, 0);
        f32x4 d0_ = MFMA16(WI0a, xf0, cb1a);
        f32x4 d1_ = MFMA16(WI0b, xf0, cb1b);
#pragma unroll
        for (int i = 0; i < 4; ++i) { d0_[i] = fast_tanh(d0_[i]); d1_[i] = fast_tanh(d1_[i]); }
#pragma unroll
        for (int i = 0; i < 4; ++i) { h1f[i] = (_Float16)d0_[i]; h1f[4+i] = (_Float16)d1_[i]; }
        STEP(0, 1); STEP(0, 2); STEP(0, 3);
        STEP(0, 4); STEP(0, 5); STEP(0, 6); STEP(0, 7);
    }

    // chunks 1..252, staging 3 ahead; never wait on recent loads
    for (int k = 0; k < 63; ++k) {
        STAGE(0); WAITV(48); CHUNK8(1);
        STAGE(1); WAITV(48); CHUNK8(2);
        STAGE(2); WAITV(48); CHUNK8(3);
        STAGE(3); WAITV(48); CHUNK8(0);
    }
    // chunks 253..255 (staged; drain)
    WAITV(32); CHUNK8(1);
    WAITV(16); CHUNK8(2);
    WAITV(0);  CHUNK8(3);

    {   // final layer-2-only step: h2(2047) from h1(2047), h2(2046)
        f32x4 e0_ = MFMA16(WI1a, h1f, cb2a);
        f32x4 e1_ = MFMA16(WI1b, h1f, cb2b);
        e0_ = MFMA16(WH1a, h2f, e0_);
        e1_ = MFMA16(WH1b, h2f, e1_);
#pragma unroll
        for (int i = 0; i < 4; ++i) { e0_[i] = fast_tanh(e0_[i]); e1_[i] = fast_tanh(e1_[i]); }
#pragma unroll
        for (int i = 0; i < 4; ++i) {
            h2fin[n][4*g + i]      = e0_[i];
            h2fin[n][16 + 4*g + i] = e1_[i];
        }
    }
#undef STEP
#undef CHUNK8
#undef LOADX
#undef CVTX
#undef STAGE
#undef WAITV

    __syncthreads();

    for (int c = ln; c < 16 * RC; c += 64) {
        const int bt = c / RC;
        const int cl = c % RC;
        float s = fc_b[cl];
#pragma unroll
        for (int kk = 0; kk < RH; ++kk)
            s = fmaf(fc_w[cl*RH + kk], h2fin[bt][kk], s);
        out[(size_t)(blockIdx.x*16 + bt) * RC + cl] = s;
    }
}

extern "C" void kernel_launch(void* const* d_in, const int* in_sizes, int n_in,
                              void* d_out, int out_size, void* d_ws, size_t ws_size,
                              hipStream_t stream) {
    const float* x     = (const float*)d_in[0];
    const float* W_ih0 = (const float*)d_in[1];
    const float* W_hh0 = (const float*)d_in[2];
    const float* b_ih0 = (const float*)d_in[3];
    const float* b_hh0 = (const float*)d_in[4];
    const float* W_ih1 = (const float*)d_in[5];
    const float* W_hh1 = (const float*)d_in[6];
    const float* b_ih1 = (const float*)d_in[7];
    const float* b_hh1 = (const float*)d_in[8];
    const float* fc_w  = (const float*)d_in[9];
    const float* fc_b  = (const float*)d_in[10];
    float* out = (float*)d_out;

    rnn2_ldsx_kernel<<<32, 64, 0, stream>>>(x, W_ih0, W_hh0, b_ih0, b_hh0,
                                            W_ih1, W_hh1, b_ih1, b_hh1,
                                            fc_w, fc_b, out);
}